// Round 14
// baseline (2142.954 us; speedup 1.0000x reference)
//
#include <hip/hip_runtime.h>
#include <math.h>

#define DIM 66
#define NPATH 17
#define WNUM 648
#define NHID 32

// ---------------- CG computation (device, mirrors reference exactly) ----------------

__device__ double dfact(int n){ double f=1.0; for(int i=2;i<=n;i++) f*=(double)i; return f; }

__device__ double su2_cg(int j1,int j2,int j3,int m1,int m2,int m3){
  if(m1+m2!=m3) return 0.0;
  double pre = sqrt((double)(2*j3+1)*dfact(j3+j1-j2)*dfact(j3-j1+j2)*dfact(j1+j2-j3)/dfact(j1+j2+j3+1));
  pre *= sqrt(dfact(j3+m3)*dfact(j3-m3)*dfact(j1-m1)*dfact(j1+m1)*dfact(j2-m2)*dfact(j2+m2));
  double s=0.0;
  for(int k=0;k<=j1+j2-j3;k++){
    int a0=k, a1=j1+j2-j3-k, a2=j1-m1-k, a3=j2+m2-k, a4=j3-j2+m1+k, a5=j3-j1-m2+k;
    if(a0<0||a1<0||a2<0||a3<0||a4<0||a5<0) continue;
    double d = dfact(a0)*dfact(a1)*dfact(a2)*dfact(a3)*dfact(a4)*dfact(a5);
    s += ((k&1)? -1.0:1.0)/d;
  }
  return pre*s;
}

// U_real(l)[row,col] (complex); row m = row-l
__device__ void u_real_entry(int l, int row, int col, double& re, double& im){
  re=0.0; im=0.0;
  const double sq = 0.7071067811865476;
  int m = row - l;
  if(m>0){
    if(col==l+m) re = ((m&1)? -sq : sq);
    else if(col==l-m) re = sq;
  } else if(m==0){
    if(col==l) re = 1.0;
  } else {
    int am = -m;
    if(col==l+m) im = sq;                      // 1j*sq
    else if(col==l-m) im = ((am&1)? sq : -sq); // -1j*(-1)^m*sq
  }
}

__constant__ int c_l1[NPATH]   = {0,0,0,1,1,1,1,1,1,1,1,1,2,2,2,2,2};
__constant__ int c_l2[NPATH]   = {0,1,2,0,1,1,1,2,0,1,2,2,0,1,2,2,2};
__constant__ int c_l3[NPATH]   = {0,1,2,1,0,1,2,1,1,1,1,2,2,1,0,1,2};
__constant__ int c_cgoff[NPATH]= {0,1,10,35,44,53,80,125,170,179,206,251,326,351,396,421,496};

__global__ void cg_init_kernel(float* __restrict__ cg_out){
  int p = blockIdx.x;
  int l1=c_l1[p], l2=c_l2[p], l3=c_l3[p];
  int n1=2*l1+1, n2=2*l2+1, n3=2*l3+1;
  int ntot=n1*n2*n3;
  __shared__ double Cc[125];
  __shared__ double red[128];
  int t=threadIdx.x;
  if(t<ntot){
    int i=t/(n2*n3), j=(t/n3)%n2, k=t%n3;
    Cc[t] = su2_cg(l1,l2,l3,i-l1,j-l2,k-l3);
  }
  __syncthreads();
  double Tre=0.0, Tim=0.0;
  if(t<ntot){
    int a=t/(n2*n3), b=(t/n3)%n2, c=t%n3;
    for(int i=0;i<n1;i++)for(int j=0;j<n2;j++)for(int k=0;k<n3;k++){
      double cc=Cc[(i*n2+j)*n3+k];
      if(cc==0.0) continue;
      double u1r,u1i,u2r,u2i,u3r,u3i;
      u_real_entry(l1,a,i,u1r,u1i); u1i=-u1i;   // conj
      u_real_entry(l2,b,j,u2r,u2i); u2i=-u2i;   // conj
      u_real_entry(l3,c,k,u3r,u3i);
      double pr=u1r*u2r-u1i*u2i, pi=u1r*u2i+u1i*u2r;
      double qr=pr*u3r-pi*u3i,   qi=pr*u3i+pi*u3r;
      Tre+=qr*cc; Tim+=qi*cc;
    }
  }
  red[t]=fabs(Tre); __syncthreads();
  for(int s=64;s>0;s>>=1){ if(t<s) red[t]+=red[t+s]; __syncthreads(); }
  double sar=red[0]; __syncthreads();
  red[t]=fabs(Tim); __syncthreads();
  for(int s=64;s>0;s>>=1){ if(t<s) red[t]+=red[t+s]; __syncthreads(); }
  double sai=red[0]; __syncthreads();
  double chosen = (sar>=sai)? Tre : Tim;
  red[t]=chosen*chosen; __syncthreads();
  for(int s=64;s>0;s>>=1){ if(t<s) red[t]+=red[t+s]; __syncthreads(); }
  double nrm=sqrt(red[0]);
  if(t<ntot) cg_out[c_cgoff[p]+t] = (float)(chosen/nrm);
}

// ---------------- rad_w2 transpose (+ fold 1/sqrt(32)) ----------------

__global__ void w2t_kernel(const float* __restrict__ w2, float* __restrict__ w2t){
  int i=blockIdx.x*blockDim.x+threadIdx.x;
  if(i<WNUM*NHID){
    int t=i/WNUM, c=i%WNUM;
    w2t[c*NHID+t]=w2[i]*0.17677669529663687f; // 1/sqrt(32)
  }
}

// ---------------- per-node linears: h_in (lin_in) to ws, res to d_out ----------------

__global__ void linear_kernel(const float* __restrict__ h,
  const float* __restrict__ w0i, const float* __restrict__ w1oi, const float* __restrict__ w1ei,
  const float* __restrict__ w2i, const float* __restrict__ b0i,
  const float* __restrict__ w0r, const float* __restrict__ w1or_, const float* __restrict__ w1er,
  const float* __restrict__ w2r, const float* __restrict__ b0r,
  float* __restrict__ h_in, float* __restrict__ out, int total)
{
  int idx=blockIdx.x*blockDim.x+threadIdx.x;
  if(idx>=total) return;
  int d = idx % DIM;
  long bn = idx / DIM;
  const float* hr = h + bn*(long)DIM;
  float s1=0.f, s2=0.f, o1, o2;
  if(d<12){
    #pragma unroll
    for(int u=0;u<12;u++){ float xv=hr[u]; s1+=xv*w0i[u*12+d]; s2+=xv*w0r[u*12+d]; }
    const float r = 0.28867513459481287f; // 1/sqrt(12)
    o1 = s1*r + b0i[d]; o2 = s2*r + b0r[d];
  } else if(d<24){
    int rel=d-12, v=rel/3, i=rel%3;
    #pragma unroll
    for(int u=0;u<4;u++){ float xv=hr[12+u*3+i]; s1+=xv*w1oi[u*4+v]; s2+=xv*w1or_[u*4+v]; }
    o1=s1*0.5f; o2=s2*0.5f;
  } else if(d<36){
    int rel=d-24, v=rel/3, i=rel%3;
    #pragma unroll
    for(int u=0;u<4;u++){ float xv=hr[24+u*3+i]; s1+=xv*w1ei[u*4+v]; s2+=xv*w1er[u*4+v]; }
    o1=s1*0.5f; o2=s2*0.5f;
  } else {
    int rel=d-36, v=rel/5, i=rel%5;
    #pragma unroll
    for(int u=0;u<6;u++){ float xv=hr[36+u*5+i]; s1+=xv*w2i[u*6+v]; s2+=xv*w2r[u*6+v]; }
    const float r=0.4082482904638631f; // 1/sqrt(6)
    o1=s1*r; o2=s2*r;
  }
  h_in[idx]=o1; out[idx]=o2;
}

// ---------------- edge kernel: 4-way role split, noinline bodies ----------------
// role = blockIdx.x & 3 handles output-mult channels v with v%4==role.
// __noinline__ keeps each role's regalloc separate (R5's inlined merge hit 180 VGPR).
// Adjacent blocks (same edge chunk, 4 roles) share hs rows in L2; each role's
// ~21 KB weight slice is L1-resident.

template<int ROLE,int L1_,int L2_,int L3_,int MUL1,int MULO,int XOFF,int YOFF,int OOFF,int WOFF,int CGOFF>
__device__ __forceinline__ void do_path(const float* __restrict__ hs, const float* Y, const float* hid,
  const float* __restrict__ w2t, const float* __restrict__ cg, float* acc)
{
  constexpr int N1=2*L1_+1, N2=2*L2_+1, N3=2*L3_+1;
  float M[N1*N3];
  #pragma unroll
  for(int i=0;i<N1;i++){
    #pragma unroll
    for(int k=0;k<N3;k++){
      float s=0.f;
      #pragma unroll
      for(int j=0;j<N2;j++) s += Y[YOFF+j]*cg[CGOFF+(i*N2+j)*N3+k];
      M[i*N3+k]=s;
    }
  }
  for(int u=0;u<MUL1;u++){
    float zt[N3];
    #pragma unroll
    for(int k=0;k<N3;k++){
      float s=0.f;
      #pragma unroll
      for(int i=0;i<N1;i++) s += hs[XOFF+u*N1+i]*M[i*N3+k];
      zt[k]=s;
    }
    #pragma unroll
    for(int v=0;v<MULO;v++){
      if((v & 3) != ROLE) continue;          // compile-time under unroll
      const float* wp = w2t + (WOFF+u*MULO+v)*NHID;
      float wv0=0.f, wv1=0.f;
      #pragma unroll
      for(int q=0;q<4;q++){
        float4 wa = *(const float4*)(wp + 8*q);
        float4 wb = *(const float4*)(wp + 8*q + 4);
        wv0 += wa.x*hid[8*q]   + wa.y*hid[8*q+1] + wa.z*hid[8*q+2] + wa.w*hid[8*q+3];
        wv1 += wb.x*hid[8*q+4] + wb.y*hid[8*q+5] + wb.z*hid[8*q+6] + wb.w*hid[8*q+7];
      }
      float wv = wv0 + wv1;
      #pragma unroll
      for(int k=0;k<N3;k++) acc[OOFF+v*N3+k] += zt[k]*wv;
    }
  }
}

__device__ __forceinline__ bool owned_ch(int d, int role){
  int v;
  if(d<12) v=d; else if(d<24) v=(d-12)/3; else if(d<36) v=(d-24)/3; else v=(d-36)/5;
  return (v&3)==role;
}

template<int ROLE>
__device__ __noinline__ void edge_body(int idx,
  const float* __restrict__ h_in, const int* __restrict__ e_src, const int* __restrict__ e_dst,
  const float* __restrict__ e_attr, const float* __restrict__ rad_w1, const float* __restrict__ w2t,
  const float* __restrict__ cg, float* __restrict__ out, int N, int E)
{
  int b = idx / E;
  int src = e_src[idx], dst = e_dst[idx];
  const float* ea = e_attr + (long)idx*3;
  float x=ea[0], y=ea[1], z=ea[2];
  float rn = sqrtf(x*x+y*y+z*z) + 1e-8f;
  float xh=x/rn, yh=y/rn, zh=z/rn;
  float Y[9];
  const float s3=1.7320508075688772f, s5=2.23606797749979f, s15=3.872983346207417f;
  Y[0]=1.f; Y[1]=s3*yh; Y[2]=s3*zh; Y[3]=s3*xh;
  Y[4]=s15*xh*yh; Y[5]=s15*yh*zh; Y[6]=0.5f*s5*(3.f*zh*zh-1.f);
  Y[7]=s15*xh*zh; Y[8]=0.5f*s15*(xh*xh-yh*yh);
  float hid[NHID];
  #pragma unroll
  for(int t=0;t<NHID;t++){ float a = rn*rad_w1[t]; hid[t]=a/(1.f+expf(-a)); }
  const float* hs = h_in + ((long)b*N + src)*DIM;
  float acc[DIM];
  #pragma unroll
  for(int d=0;d<DIM;d++) acc[d]=0.f;

  //              L1 L2 L3 M1 MO  XO YO OO  WOFF CGOFF
  do_path<ROLE,0,0,0,12,12,  0,0, 0,   0,   0>(hs,Y,hid,w2t,cg,acc);
  do_path<ROLE,0,1,1,12, 4,  0,1,12, 144,   1>(hs,Y,hid,w2t,cg,acc);
  do_path<ROLE,0,2,2,12, 6,  0,4,36, 192,  10>(hs,Y,hid,w2t,cg,acc);
  do_path<ROLE,1,0,1, 4, 4, 12,0,12, 264,  35>(hs,Y,hid,w2t,cg,acc);
  do_path<ROLE,1,1,0, 4,12, 12,1, 0, 280,  44>(hs,Y,hid,w2t,cg,acc);
  do_path<ROLE,1,1,1, 4, 4, 12,1,24, 328,  53>(hs,Y,hid,w2t,cg,acc);
  do_path<ROLE,1,1,2, 4, 6, 12,1,36, 344,  80>(hs,Y,hid,w2t,cg,acc);
  do_path<ROLE,1,2,1, 4, 4, 12,4,12, 368, 125>(hs,Y,hid,w2t,cg,acc);
  do_path<ROLE,1,0,1, 4, 4, 24,0,24, 384, 170>(hs,Y,hid,w2t,cg,acc);
  do_path<ROLE,1,1,1, 4, 4, 24,1,12, 400, 179>(hs,Y,hid,w2t,cg,acc);
  do_path<ROLE,1,2,1, 4, 4, 24,4,24, 416, 206>(hs,Y,hid,w2t,cg,acc);
  do_path<ROLE,1,2,2, 4, 6, 24,4,36, 432, 251>(hs,Y,hid,w2t,cg,acc);
  do_path<ROLE,2,0,2, 6, 6, 36,0,36, 456, 326>(hs,Y,hid,w2t,cg,acc);
  do_path<ROLE,2,1,1, 6, 4, 36,1,12, 492, 351>(hs,Y,hid,w2t,cg,acc);
  do_path<ROLE,2,2,0, 6,12, 36,4, 0, 516, 396>(hs,Y,hid,w2t,cg,acc);
  do_path<ROLE,2,2,1, 6, 4, 36,4,24, 588, 421>(hs,Y,hid,w2t,cg,acc);
  do_path<ROLE,2,2,2, 6, 6, 36,4,36, 612, 496>(hs,Y,hid,w2t,cg,acc);

  const float a0=0.21320071635561044f; // sqrt(1/22)
  const float a1=0.31622776601683794f; // sqrt(3/30)
  const float a2=0.4082482904638631f;  // sqrt(3/18)
  const float a3=0.3952847075210474f;  // sqrt(5/32)
  float* op = out + ((long)b*N + dst)*DIM;
  #pragma unroll
  for(int d=0;d<12;d++)  if(owned_ch(d,ROLE)) unsafeAtomicAdd(&op[d], acc[d]*a0);
  #pragma unroll
  for(int d=12;d<24;d++) if(owned_ch(d,ROLE)) unsafeAtomicAdd(&op[d], acc[d]*a1);
  #pragma unroll
  for(int d=24;d<36;d++) if(owned_ch(d,ROLE)) unsafeAtomicAdd(&op[d], acc[d]*a2);
  #pragma unroll
  for(int d=36;d<66;d++) if(owned_ch(d,ROLE)) unsafeAtomicAdd(&op[d], acc[d]*a3);
}

__global__ __launch_bounds__(64, 4) void edge_kernel(
  const float* __restrict__ h_in, const int* __restrict__ e_src, const int* __restrict__ e_dst,
  const float* __restrict__ e_attr, const float* __restrict__ rad_w1, const float* __restrict__ w2t,
  const float* __restrict__ cg, float* __restrict__ out, int total, int N, int E)
{
  int role = blockIdx.x & 3;
  int idx  = (blockIdx.x >> 2)*64 + threadIdx.x;
  if(idx>=total) return;
  switch(role){
    case 0: edge_body<0>(idx,h_in,e_src,e_dst,e_attr,rad_w1,w2t,cg,out,N,E); break;
    case 1: edge_body<1>(idx,h_in,e_src,e_dst,e_attr,rad_w1,w2t,cg,out,N,E); break;
    case 2: edge_body<2>(idx,h_in,e_src,e_dst,e_attr,rad_w1,w2t,cg,out,N,E); break;
    default: edge_body<3>(idx,h_in,e_src,e_dst,e_attr,rad_w1,w2t,cg,out,N,E); break;
  }
}

// ---------------- norm_act (in place on d_out) ----------------

__global__ void norm_act_kernel(float* __restrict__ out, int total){
  int idx=blockIdx.x*blockDim.x+threadIdx.x;
  if(idx>=total) return;
  int c = idx % 26; long bn = idx / 26;
  int off, len;
  if(c<12){ off=c; len=1; }
  else if(c<16){ off=12+(c-12)*3; len=3; }
  else if(c<20){ off=24+(c-16)*3; len=3; }
  else { off=36+(c-20)*5; len=5; }
  float* p = out + bn*(long)DIM + off;
  float sum=0.f;
  for(int i=0;i<len;i++){ float v=p[i]; sum+=v*v; }
  float n = sqrtf(sum+1e-12f);
  float sc = 1.f/(1.f+expf(-n));  // silu(n)/n = sigmoid(n)
  for(int i=0;i<len;i++) p[i]*=sc;
}

// ---------------- launch ----------------

extern "C" void kernel_launch(void* const* d_in, const int* in_sizes, int n_in,
                              void* d_out, int out_size, void* d_ws, size_t ws_size,
                              hipStream_t stream)
{
  const float* h       = (const float*)d_in[0];
  const int*   e_src   = (const int*)  d_in[1];
  const int*   e_dst   = (const int*)  d_in[2];
  const float* e_attr  = (const float*)d_in[3];
  const float* lw0     = (const float*)d_in[4];
  const float* lw1o    = (const float*)d_in[5];
  const float* lw1e    = (const float*)d_in[6];
  const float* lw2     = (const float*)d_in[7];
  const float* lb0     = (const float*)d_in[8];
  const float* rw0     = (const float*)d_in[9];
  const float* rw1o    = (const float*)d_in[10];
  const float* rw1e    = (const float*)d_in[11];
  const float* rw2     = (const float*)d_in[12];
  const float* rb0     = (const float*)d_in[13];
  const float* rad_w1  = (const float*)d_in[14];
  const float* rad_w2  = (const float*)d_in[15];

  const int B  = 2;
  const int BE = in_sizes[1];        // B*E
  const int E  = BE / B;
  const int BN = in_sizes[0] / DIM;  // B*N
  const int N  = BN / B;

  float* ws   = (float*)d_ws;
  float* h_in = ws;                           // BN*DIM floats
  float* cg   = ws + (size_t)BN*DIM;          // 621 floats (pad to 640)
  float* w2t  = cg + 640;                     // WNUM*NHID floats

  cg_init_kernel<<<NPATH, 128, 0, stream>>>(cg);
  int w2n = WNUM*NHID;
  w2t_kernel<<<(w2n+255)/256, 256, 0, stream>>>(rad_w2, w2t);
  int totL = BN*DIM;
  linear_kernel<<<(totL+255)/256, 256, 0, stream>>>(h, lw0, lw1o, lw1e, lw2, lb0,
                                                    rw0, rw1o, rw1e, rw2, rb0,
                                                    h_in, (float*)d_out, totL);
  int eblk64 = (BE+63)/64;
  edge_kernel<<<eblk64*4, 64, 0, stream>>>(h_in, e_src, e_dst, e_attr,
                                           rad_w1, w2t, cg, (float*)d_out, BE, N, E);
  int totN = BN*26;
  norm_act_kernel<<<(totN+255)/256, 256, 0, stream>>>((float*)d_out, totN);
}

// Round 15
// 688.433 us; speedup vs baseline: 3.1128x; 3.1128x over previous
//
#include <hip/hip_runtime.h>
#include <math.h>

#define DIM 66
#define NPATH 17
#define WNUM 648
#define NHID 32
#define HSTR 67   // hs LDS row stride (67: gcd(67,32)=1 -> 2-way max, free)

// ---------------- CG computation (device, mirrors reference exactly) ----------------

__device__ double dfact(int n){ double f=1.0; for(int i=2;i<=n;i++) f*=(double)i; return f; }

__device__ double su2_cg(int j1,int j2,int j3,int m1,int m2,int m3){
  if(m1+m2!=m3) return 0.0;
  double pre = sqrt((double)(2*j3+1)*dfact(j3+j1-j2)*dfact(j3-j1+j2)*dfact(j1+j2-j3)/dfact(j1+j2+j3+1));
  pre *= sqrt(dfact(j3+m3)*dfact(j3-m3)*dfact(j1-m1)*dfact(j1+m1)*dfact(j2-m2)*dfact(j2+m2));
  double s=0.0;
  for(int k=0;k<=j1+j2-j3;k++){
    int a0=k, a1=j1+j2-j3-k, a2=j1-m1-k, a3=j2+m2-k, a4=j3-j2+m1+k, a5=j3-j1-m2+k;
    if(a0<0||a1<0||a2<0||a3<0||a4<0||a5<0) continue;
    double d = dfact(a0)*dfact(a1)*dfact(a2)*dfact(a3)*dfact(a4)*dfact(a5);
    s += ((k&1)? -1.0:1.0)/d;
  }
  return pre*s;
}

// U_real(l)[row,col] (complex); row m = row-l
__device__ void u_real_entry(int l, int row, int col, double& re, double& im){
  re=0.0; im=0.0;
  const double sq = 0.7071067811865476;
  int m = row - l;
  if(m>0){
    if(col==l+m) re = ((m&1)? -sq : sq);
    else if(col==l-m) re = sq;
  } else if(m==0){
    if(col==l) re = 1.0;
  } else {
    int am = -m;
    if(col==l+m) im = sq;                      // 1j*sq
    else if(col==l-m) im = ((am&1)? sq : -sq); // -1j*(-1)^m*sq
  }
}

__constant__ int c_l1[NPATH]   = {0,0,0,1,1,1,1,1,1,1,1,1,2,2,2,2,2};
__constant__ int c_l2[NPATH]   = {0,1,2,0,1,1,1,2,0,1,2,2,0,1,2,2,2};
__constant__ int c_l3[NPATH]   = {0,1,2,1,0,1,2,1,1,1,1,2,2,1,0,1,2};
__constant__ int c_cgoff[NPATH]= {0,1,10,35,44,53,80,125,170,179,206,251,326,351,396,421,496};

__global__ void cg_init_kernel(float* __restrict__ cg_out){
  int p = blockIdx.x;
  int l1=c_l1[p], l2=c_l2[p], l3=c_l3[p];
  int n1=2*l1+1, n2=2*l2+1, n3=2*l3+1;
  int ntot=n1*n2*n3;
  __shared__ double Cc[125];
  __shared__ double red[128];
  int t=threadIdx.x;
  if(t<ntot){
    int i=t/(n2*n3), j=(t/n3)%n2, k=t%n3;
    Cc[t] = su2_cg(l1,l2,l3,i-l1,j-l2,k-l3);
  }
  __syncthreads();
  double Tre=0.0, Tim=0.0;
  if(t<ntot){
    int a=t/(n2*n3), b=(t/n3)%n2, c=t%n3;
    for(int i=0;i<n1;i++)for(int j=0;j<n2;j++)for(int k=0;k<n3;k++){
      double cc=Cc[(i*n2+j)*n3+k];
      if(cc==0.0) continue;
      double u1r,u1i,u2r,u2i,u3r,u3i;
      u_real_entry(l1,a,i,u1r,u1i); u1i=-u1i;   // conj
      u_real_entry(l2,b,j,u2r,u2i); u2i=-u2i;   // conj
      u_real_entry(l3,c,k,u3r,u3i);
      double pr=u1r*u2r-u1i*u2i, pi=u1r*u2i+u1i*u2r;
      double qr=pr*u3r-pi*u3i,   qi=pr*u3i+pi*u3r;
      Tre+=qr*cc; Tim+=qi*cc;
    }
  }
  red[t]=fabs(Tre); __syncthreads();
  for(int s=64;s>0;s>>=1){ if(t<s) red[t]+=red[t+s]; __syncthreads(); }
  double sar=red[0]; __syncthreads();
  red[t]=fabs(Tim); __syncthreads();
  for(int s=64;s>0;s>>=1){ if(t<s) red[t]+=red[t+s]; __syncthreads(); }
  double sai=red[0]; __syncthreads();
  double chosen = (sar>=sai)? Tre : Tim;
  red[t]=chosen*chosen; __syncthreads();
  for(int s=64;s>0;s>>=1){ if(t<s) red[t]+=red[t+s]; __syncthreads(); }
  double nrm=sqrt(red[0]);
  if(t<ntot) cg_out[c_cgoff[p]+t] = (float)(chosen/nrm);
}

// ------- rad_w2 repack: transpose + fold 1/sqrt(32) + group-contiguous row order -------
// New row order: [group0 rows][group1][group2][group3]; bases 0,264,384,456.

__constant__ int rp_old[NPATH] = {0,144,192,264,280,328,344,368,384,400,416,432,456,492,516,588,612};
__constant__ int rp_cnt[NPATH] = {144,48,72,16,48,16,24,16,16,16,16,24,36,24,72,24,36};
__constant__ int rp_new[NPATH] = {0,264,456,312,144,384,528,328,400,344,416,552,576,360,192,432,612};

__global__ void wg_pack_kernel(const float* __restrict__ w2, float* __restrict__ wg){
  int i=blockIdx.x*blockDim.x+threadIdx.x;
  if(i>=WNUM*NHID) return;
  int t=i/WNUM, c=i%WNUM;            // input layout [32][648]
  int nr=0;
  #pragma unroll
  for(int p=0;p<NPATH;p++)
    if(c>=rp_old[p] && c<rp_old[p]+rp_cnt[p]) nr = rp_new[p] + (c-rp_old[p]);
  wg[nr*NHID+t] = w2[i]*0.17677669529663687f; // 1/sqrt(32)
}

// ---------------- per-node linears: h_in (lin_in) to ws, res to d_out ----------------

__global__ void linear_kernel(const float* __restrict__ h,
  const float* __restrict__ w0i, const float* __restrict__ w1oi, const float* __restrict__ w1ei,
  const float* __restrict__ w2i, const float* __restrict__ b0i,
  const float* __restrict__ w0r, const float* __restrict__ w1or_, const float* __restrict__ w1er,
  const float* __restrict__ w2r, const float* __restrict__ b0r,
  float* __restrict__ h_in, float* __restrict__ out, int total)
{
  int idx=blockIdx.x*blockDim.x+threadIdx.x;
  if(idx>=total) return;
  int d = idx % DIM;
  long bn = idx / DIM;
  const float* hr = h + bn*(long)DIM;
  float s1=0.f, s2=0.f, o1, o2;
  if(d<12){
    #pragma unroll
    for(int u=0;u<12;u++){ float xv=hr[u]; s1+=xv*w0i[u*12+d]; s2+=xv*w0r[u*12+d]; }
    const float r = 0.28867513459481287f; // 1/sqrt(12)
    o1 = s1*r + b0i[d]; o2 = s2*r + b0r[d];
  } else if(d<24){
    int rel=d-12, v=rel/3, i=rel%3;
    #pragma unroll
    for(int u=0;u<4;u++){ float xv=hr[12+u*3+i]; s1+=xv*w1oi[u*4+v]; s2+=xv*w1or_[u*4+v]; }
    o1=s1*0.5f; o2=s2*0.5f;
  } else if(d<36){
    int rel=d-24, v=rel/3, i=rel%3;
    #pragma unroll
    for(int u=0;u<4;u++){ float xv=hr[24+u*3+i]; s1+=xv*w1ei[u*4+v]; s2+=xv*w1er[u*4+v]; }
    o1=s1*0.5f; o2=s2*0.5f;
  } else {
    int rel=d-36, v=rel/5, i=rel%5;
    #pragma unroll
    for(int u=0;u<6;u++){ float xv=hr[36+u*5+i]; s1+=xv*w2i[u*6+v]; s2+=xv*w2r[u*6+v]; }
    const float r=0.4082482904638631f; // 1/sqrt(6)
    o1=s1*r; o2=s2*r;
  }
  h_in[idx]=o1; out[idx]=o2;
}

// ---------------- fused edge kernel: in-LDS wv GEMM + role-split consumption --------
// block = 256 threads = 4 waves x 64 edges.
// Phase A (per chunk): waves cooperatively compute wv[row][64] into LDS
//   (weight rows = wave-uniform L1-broadcast loads; hid per-lane registers).
// Phase B: wave g consumes output-mult v == g (mod 4); zt from LDS-staged hs;
//   weight dot replaced by ONE stride-1 LDS read wv[row][lane].

template<int L1_,int L2_,int L3_,int MUL1,int MULO,int U0,int U1,int XOFF,int YOFF,int WROW,int CGOFF,int OACC>
__device__ __forceinline__ void do_path_rs(const float* __restrict__ hsr, const float* Y,
  const float* __restrict__ wvl, int wave, int lane, const float* __restrict__ cgl, float* acc)
{
  constexpr int N1=2*L1_+1, N2=2*L2_+1, N3=2*L3_+1;
  constexpr int NJ=(MULO+3)/4;
  float M[N1*N3];
  #pragma unroll
  for(int i=0;i<N1;i++){
    #pragma unroll
    for(int k=0;k<N3;k++){
      float s=0.f;
      #pragma unroll
      for(int j=0;j<N2;j++) s += Y[YOFF+j]*cgl[CGOFF+(i*N2+j)*N3+k];
      M[i*N3+k]=s;
    }
  }
  for(int u=U0; u<U1; u++){
    float zt[N3];
    #pragma unroll
    for(int k=0;k<N3;k++){
      float s=0.f;
      #pragma unroll
      for(int i=0;i<N1;i++) s += hsr[XOFF+u*N1+i]*M[i*N3+k];
      zt[k]=s;
    }
    #pragma unroll
    for(int j=0;j<NJ;j++){
      int v = 4*j + wave;                 // runtime but wave-uniform
      if(v < MULO){
        float w = wvl[(WROW + (u-U0)*MULO + v)*64 + lane];  // stride-1, no conflict
        #pragma unroll
        for(int k=0;k<N3;k++) acc[OACC + j*N3 + k] += zt[k]*w;   // static acc index
      }
    }
  }
}

#define GEMM_CHUNK(GROW, NROWS) \
  __syncthreads(); \
  for(int r=wave; r<(NROWS); r+=4){ \
    const float* wr = wg + (GROW + r)*NHID; \
    float s0=0.f, s1=0.f; \
    _Pragma("unroll") \
    for(int q=0;q<4;q++){ \
      float4 wa=*(const float4*)(wr+8*q); \
      float4 wb=*(const float4*)(wr+8*q+4); \
      s0+=wa.x*hid[8*q]  +wa.y*hid[8*q+1]+wa.z*hid[8*q+2]+wa.w*hid[8*q+3]; \
      s1+=wb.x*hid[8*q+4]+wb.y*hid[8*q+5]+wb.z*hid[8*q+6]+wb.w*hid[8*q+7]; \
    } \
    wvl[r*64+lane]=s0+s1; \
  } \
  __syncthreads();

__global__ __launch_bounds__(256, 3) void edge_fused_kernel(
  const float* __restrict__ h_in, const int* __restrict__ e_src, const int* __restrict__ e_dst,
  const float* __restrict__ e_attr, const float* __restrict__ rad_w1,
  const float* __restrict__ wg, const float* __restrict__ cg, float* __restrict__ out,
  int BE, int N, int E)
{
  __shared__ float hsl[64*HSTR];   // 17.2 KB staged h_in rows
  __shared__ float wvl[120*64];    // 30.7 KB wv chunk
  __shared__ float cgl[640];
  int tid  = threadIdx.x;
  int lane = tid & 63;
  int wave = tid >> 6;
  int e0   = blockIdx.x*64;
  int el   = e0 + lane;
  bool active = el < BE;

  for(int i=tid; i<621; i+=256) cgl[i]=cg[i];

  // stage hs rows (gather once per block)
  for(int i=tid; i<64*DIM; i+=256){
    int e=i/DIM, d=i-e*DIM;
    int ee=e0+e;
    float v=0.f;
    if(ee<BE){
      int bb=ee/E;
      int s=e_src[ee];
      v=h_in[((long)bb*N+s)*DIM+d];
    }
    hsl[e*HSTR+d]=v;
  }

  // per-lane edge data (each wave redundantly for its lane-edge)
  int b=0,dst=0;
  float x=0.f,y=0.f,z=0.f;
  if(active){
    b=el/E; dst=e_dst[el];
    const float* ea=e_attr+(long)el*3;
    x=ea[0]; y=ea[1]; z=ea[2];
  }
  float rn=sqrtf(x*x+y*y+z*z)+1e-8f;
  float xh=x/rn, yh=y/rn, zh=z/rn;
  float Y[9];
  const float s3=1.7320508075688772f, s5=2.23606797749979f, s15=3.872983346207417f;
  Y[0]=1.f; Y[1]=s3*yh; Y[2]=s3*zh; Y[3]=s3*xh;
  Y[4]=s15*xh*yh; Y[5]=s15*yh*zh; Y[6]=0.5f*s5*(3.f*zh*zh-1.f);
  Y[7]=s15*xh*zh; Y[8]=0.5f*s15*(xh*xh-yh*yh);
  float hid[NHID];
  #pragma unroll
  for(int t=0;t<NHID;t++){ float a=rn*rad_w1[t]; hid[t]=a/(1.f+expf(-a)); }
  const float* hsr = hsl + lane*HSTR;
  float* op = out + ((long)b*N + dst)*DIM;
  float acc[19];
  #pragma unroll
  for(int i=0;i<19;i++) acc[i]=0.f;

  // ---- chunk schedule (R13-verified tables; wg group-packed row order) ----
  GEMM_CHUNK(0, 120)    // K0: (0,0,0) u0-9
  //          L1 L2 L3 M1 MO  U0 U1  XO YO WROW CGOFF OACC
  do_path_rs<0,0,0,12,12,  0,10,  0,0,   0,   0, 0>(hsr,Y,wvl,wave,lane,cgl,acc);
  GEMM_CHUNK(120, 120)  // K1: (0,0,0) u10-11 | (1,1,0) | (2,2,0) u0-3
  do_path_rs<0,0,0,12,12, 10,12,  0,0,   0,   0, 0>(hsr,Y,wvl,wave,lane,cgl,acc);
  do_path_rs<1,1,0, 4,12,  0, 4, 12,1,  24,  44, 0>(hsr,Y,wvl,wave,lane,cgl,acc);
  do_path_rs<2,2,0, 6,12,  0, 4, 36,4,  72, 396, 0>(hsr,Y,wvl,wave,lane,cgl,acc);
  GEMM_CHUNK(240, 24)   // K2: (2,2,0) u4-5
  do_path_rs<2,2,0, 6,12,  4, 6, 36,4,   0, 396, 0>(hsr,Y,wvl,wave,lane,cgl,acc);
  GEMM_CHUNK(264, 120)  // K3: group 1
  do_path_rs<0,1,1,12, 4,  0,12,  0,1,   0,   1, 3>(hsr,Y,wvl,wave,lane,cgl,acc);
  do_path_rs<1,0,1, 4, 4,  0, 4, 12,0,  48,  35, 3>(hsr,Y,wvl,wave,lane,cgl,acc);
  do_path_rs<1,2,1, 4, 4,  0, 4, 12,4,  64, 125, 3>(hsr,Y,wvl,wave,lane,cgl,acc);
  do_path_rs<1,1,1, 4, 4,  0, 4, 24,1,  80, 179, 3>(hsr,Y,wvl,wave,lane,cgl,acc);
  do_path_rs<2,1,1, 6, 4,  0, 6, 36,1,  96, 351, 3>(hsr,Y,wvl,wave,lane,cgl,acc);
  GEMM_CHUNK(384, 72)   // K4: group 2
  do_path_rs<1,1,1, 4, 4,  0, 4, 12,1,   0,  53, 6>(hsr,Y,wvl,wave,lane,cgl,acc);
  do_path_rs<1,0,1, 4, 4,  0, 4, 24,0,  16, 170, 6>(hsr,Y,wvl,wave,lane,cgl,acc);
  do_path_rs<1,2,1, 4, 4,  0, 4, 24,4,  32, 206, 6>(hsr,Y,wvl,wave,lane,cgl,acc);
  do_path_rs<2,2,1, 6, 4,  0, 6, 36,4,  48, 421, 6>(hsr,Y,wvl,wave,lane,cgl,acc);
  GEMM_CHUNK(456, 120)  // K5: group 3 part 1
  do_path_rs<0,2,2,12, 6,  0,12,  0,4,   0,  10, 9>(hsr,Y,wvl,wave,lane,cgl,acc);
  do_path_rs<1,1,2, 4, 6,  0, 4, 12,1,  72,  80, 9>(hsr,Y,wvl,wave,lane,cgl,acc);
  do_path_rs<1,2,2, 4, 6,  0, 4, 24,4,  96, 251, 9>(hsr,Y,wvl,wave,lane,cgl,acc);
  GEMM_CHUNK(576, 72)   // K6: group 3 part 2
  do_path_rs<2,0,2, 6, 6,  0, 6, 36,0,   0, 326, 9>(hsr,Y,wvl,wave,lane,cgl,acc);
  do_path_rs<2,2,2, 6, 6,  0, 6, 36,4,  36, 496, 9>(hsr,Y,wvl,wave,lane,cgl,acc);

  // ---- atomic scatter: each wave writes its owned channels ----
  if(active){
    const float a0=0.21320071635561044f; // sqrt(1/22)
    const float a1=0.31622776601683794f; // sqrt(3/30)
    const float a2=0.4082482904638631f;  // sqrt(3/18)
    const float a3=0.3952847075210474f;  // sqrt(5/32)
    #pragma unroll
    for(int j=0;j<3;j++) unsafeAtomicAdd(&op[4*j+wave], acc[j]*a0);          // g0
    #pragma unroll
    for(int k=0;k<3;k++) unsafeAtomicAdd(&op[12+wave*3+k], acc[3+k]*a1);     // g1
    #pragma unroll
    for(int k=0;k<3;k++) unsafeAtomicAdd(&op[24+wave*3+k], acc[6+k]*a2);     // g2
    #pragma unroll
    for(int j=0;j<2;j++){                                                     // g3
      int v=4*j+wave;
      if(v<6){
        #pragma unroll
        for(int k=0;k<5;k++) unsafeAtomicAdd(&op[36+v*5+k], acc[9+5*j+k]*a3);
      }
    }
  }
}

// ---------------- norm_act (in place on d_out) ----------------

__global__ void norm_act_kernel(float* __restrict__ out, int total){
  int idx=blockIdx.x*blockDim.x+threadIdx.x;
  if(idx>=total) return;
  int c = idx % 26; long bn = idx / 26;
  int off, len;
  if(c<12){ off=c; len=1; }
  else if(c<16){ off=12+(c-12)*3; len=3; }
  else if(c<20){ off=24+(c-16)*3; len=3; }
  else { off=36+(c-20)*5; len=5; }
  float* p = out + bn*(long)DIM + off;
  float sum=0.f;
  for(int i=0;i<len;i++){ float v=p[i]; sum+=v*v; }
  float n = sqrtf(sum+1e-12f);
  float sc = 1.f/(1.f+expf(-n));  // silu(n)/n = sigmoid(n)
  for(int i=0;i<len;i++) p[i]*=sc;
}

// ---------------- launch ----------------

extern "C" void kernel_launch(void* const* d_in, const int* in_sizes, int n_in,
                              void* d_out, int out_size, void* d_ws, size_t ws_size,
                              hipStream_t stream)
{
  const float* h       = (const float*)d_in[0];
  const int*   e_src   = (const int*)  d_in[1];
  const int*   e_dst   = (const int*)  d_in[2];
  const float* e_attr  = (const float*)d_in[3];
  const float* lw0     = (const float*)d_in[4];
  const float* lw1o    = (const float*)d_in[5];
  const float* lw1e    = (const float*)d_in[6];
  const float* lw2     = (const float*)d_in[7];
  const float* lb0     = (const float*)d_in[8];
  const float* rw0     = (const float*)d_in[9];
  const float* rw1o    = (const float*)d_in[10];
  const float* rw1e    = (const float*)d_in[11];
  const float* rw2     = (const float*)d_in[12];
  const float* rb0     = (const float*)d_in[13];
  const float* rad_w1  = (const float*)d_in[14];
  const float* rad_w2  = (const float*)d_in[15];

  const int B  = 2;
  const int BE = in_sizes[1];        // B*E
  const int E  = BE / B;
  const int BN = in_sizes[0] / DIM;  // B*N
  const int N  = BN / B;

  float* ws   = (float*)d_ws;
  float* h_in = ws;                                   // BN*DIM floats
  float* cg   = ws + (size_t)BN*DIM;                  // 621 floats (pad to 640)
  float* wg   = cg + 640;                             // WNUM*NHID floats (group-packed)

  cg_init_kernel<<<NPATH, 128, 0, stream>>>(cg);
  int w2n = WNUM*NHID;
  wg_pack_kernel<<<(w2n+255)/256, 256, 0, stream>>>(rad_w2, wg);
  int totL = BN*DIM;
  linear_kernel<<<(totL+255)/256, 256, 0, stream>>>(h, lw0, lw1o, lw1e, lw2, lb0,
                                                    rw0, rw1o, rw1e, rw2, rb0,
                                                    h_in, (float*)d_out, totL);
  int eblk = (BE+63)/64;
  edge_fused_kernel<<<eblk, 256, 0, stream>>>(h_in, e_src, e_dst, e_attr,
                                              rad_w1, wg, cg, (float*)d_out,
                                              BE, N, E);
  int totN = BN*26;
  norm_act_kernel<<<(totN+255)/256, 256, 0, stream>>>((float*)d_out, totN);
}

// Round 16
// 479.650 us; speedup vs baseline: 4.4677x; 1.4353x over previous
//
#include <hip/hip_runtime.h>
#include <math.h>

#define DIM 66
#define NPATH 17
#define WNUM 648
#define NHID 32
#define HSTR 67   // hs LDS row stride (gcd(67,32)=1 -> conflict-free)
#define HPAD 40   // Hlds halves per edge (80B stride, 16B-aligned b128)
#define WROWS 656 // 648 rounded to 16

typedef _Float16 f16x8 __attribute__((ext_vector_type(8)));
typedef float f32x4 __attribute__((ext_vector_type(4)));

// ---------------- CG computation (device, mirrors reference exactly) ----------------

__device__ double dfact(int n){ double f=1.0; for(int i=2;i<=n;i++) f*=(double)i; return f; }

__device__ double su2_cg(int j1,int j2,int j3,int m1,int m2,int m3){
  if(m1+m2!=m3) return 0.0;
  double pre = sqrt((double)(2*j3+1)*dfact(j3+j1-j2)*dfact(j3-j1+j2)*dfact(j1+j2-j3)/dfact(j1+j2+j3+1));
  pre *= sqrt(dfact(j3+m3)*dfact(j3-m3)*dfact(j1-m1)*dfact(j1+m1)*dfact(j2-m2)*dfact(j2+m2));
  double s=0.0;
  for(int k=0;k<=j1+j2-j3;k++){
    int a0=k, a1=j1+j2-j3-k, a2=j1-m1-k, a3=j2+m2-k, a4=j3-j2+m1+k, a5=j3-j1-m2+k;
    if(a0<0||a1<0||a2<0||a3<0||a4<0||a5<0) continue;
    double d = dfact(a0)*dfact(a1)*dfact(a2)*dfact(a3)*dfact(a4)*dfact(a5);
    s += ((k&1)? -1.0:1.0)/d;
  }
  return pre*s;
}

__device__ void u_real_entry(int l, int row, int col, double& re, double& im){
  re=0.0; im=0.0;
  const double sq = 0.7071067811865476;
  int m = row - l;
  if(m>0){
    if(col==l+m) re = ((m&1)? -sq : sq);
    else if(col==l-m) re = sq;
  } else if(m==0){
    if(col==l) re = 1.0;
  } else {
    int am = -m;
    if(col==l+m) im = sq;
    else if(col==l-m) im = ((am&1)? sq : -sq);
  }
}

__constant__ int c_l1[NPATH]   = {0,0,0,1,1,1,1,1,1,1,1,1,2,2,2,2,2};
__constant__ int c_l2[NPATH]   = {0,1,2,0,1,1,1,2,0,1,2,2,0,1,2,2,2};
__constant__ int c_l3[NPATH]   = {0,1,2,1,0,1,2,1,1,1,1,2,2,1,0,1,2};
__constant__ int c_cgoff[NPATH]= {0,1,10,35,44,53,80,125,170,179,206,251,326,351,396,421,496};

__global__ void cg_init_kernel(float* __restrict__ cg_out){
  int p = blockIdx.x;
  int l1=c_l1[p], l2=c_l2[p], l3=c_l3[p];
  int n1=2*l1+1, n2=2*l2+1, n3=2*l3+1;
  int ntot=n1*n2*n3;
  __shared__ double Cc[125];
  __shared__ double red[128];
  int t=threadIdx.x;
  if(t<ntot){
    int i=t/(n2*n3), j=(t/n3)%n2, k=t%n3;
    Cc[t] = su2_cg(l1,l2,l3,i-l1,j-l2,k-l3);
  }
  __syncthreads();
  double Tre=0.0, Tim=0.0;
  if(t<ntot){
    int a=t/(n2*n3), b=(t/n3)%n2, c=t%n3;
    for(int i=0;i<n1;i++)for(int j=0;j<n2;j++)for(int k=0;k<n3;k++){
      double cc=Cc[(i*n2+j)*n3+k];
      if(cc==0.0) continue;
      double u1r,u1i,u2r,u2i,u3r,u3i;
      u_real_entry(l1,a,i,u1r,u1i); u1i=-u1i;
      u_real_entry(l2,b,j,u2r,u2i); u2i=-u2i;
      u_real_entry(l3,c,k,u3r,u3i);
      double pr=u1r*u2r-u1i*u2i, pi=u1r*u2i+u1i*u2r;
      double qr=pr*u3r-pi*u3i,   qi=pr*u3i+pi*u3r;
      Tre+=qr*cc; Tim+=qi*cc;
    }
  }
  red[t]=fabs(Tre); __syncthreads();
  for(int s=64;s>0;s>>=1){ if(t<s) red[t]+=red[t+s]; __syncthreads(); }
  double sar=red[0]; __syncthreads();
  red[t]=fabs(Tim); __syncthreads();
  for(int s=64;s>0;s>>=1){ if(t<s) red[t]+=red[t+s]; __syncthreads(); }
  double sai=red[0]; __syncthreads();
  double chosen = (sar>=sai)? Tre : Tim;
  red[t]=chosen*chosen; __syncthreads();
  for(int s=64;s>0;s>>=1){ if(t<s) red[t]+=red[t+s]; __syncthreads(); }
  double nrm=sqrt(red[0]);
  if(t<ntot) cg_out[c_cgoff[p]+t] = (float)(chosen/nrm);
}

// ------- W repack to f16: transpose + 1/sqrt(32) + group-contiguous rows, zero-pad to 656 -------

__constant__ int rp_old[NPATH] = {0,144,192,264,280,328,344,368,384,400,416,432,456,492,516,588,612};
__constant__ int rp_cnt[NPATH] = {144,48,72,16,48,16,24,16,16,16,16,24,36,24,72,24,36};
__constant__ int rp_new[NPATH] = {0,264,456,312,144,384,528,328,400,344,416,552,576,360,192,432,612};

__global__ void wh_pack_kernel(const float* __restrict__ w2, _Float16* __restrict__ wh){
  int i=blockIdx.x*blockDim.x+threadIdx.x;
  if(i>=WROWS*NHID) return;
  int nr=i>>5, t=i&31;
  float val=0.f;
  #pragma unroll
  for(int p=0;p<NPATH;p++){
    if(nr>=rp_new[p] && nr<rp_new[p]+rp_cnt[p]){
      int c = rp_old[p] + (nr - rp_new[p]);
      val = w2[t*WNUM + c]*0.17677669529663687f; // 1/sqrt(32)
    }
  }
  wh[i]=(_Float16)val;
}

// ---------------- per-node linears: h_in (lin_in) to ws, res to d_out ----------------

__global__ void linear_kernel(const float* __restrict__ h,
  const float* __restrict__ w0i, const float* __restrict__ w1oi, const float* __restrict__ w1ei,
  const float* __restrict__ w2i, const float* __restrict__ b0i,
  const float* __restrict__ w0r, const float* __restrict__ w1or_, const float* __restrict__ w1er,
  const float* __restrict__ w2r, const float* __restrict__ b0r,
  float* __restrict__ h_in, float* __restrict__ out, int total)
{
  int idx=blockIdx.x*blockDim.x+threadIdx.x;
  if(idx>=total) return;
  int d = idx % DIM;
  long bn = idx / DIM;
  const float* hr = h + bn*(long)DIM;
  float s1=0.f, s2=0.f, o1, o2;
  if(d<12){
    #pragma unroll
    for(int u=0;u<12;u++){ float xv=hr[u]; s1+=xv*w0i[u*12+d]; s2+=xv*w0r[u*12+d]; }
    const float r = 0.28867513459481287f;
    o1 = s1*r + b0i[d]; o2 = s2*r + b0r[d];
  } else if(d<24){
    int rel=d-12, v=rel/3, i=rel%3;
    #pragma unroll
    for(int u=0;u<4;u++){ float xv=hr[12+u*3+i]; s1+=xv*w1oi[u*4+v]; s2+=xv*w1or_[u*4+v]; }
    o1=s1*0.5f; o2=s2*0.5f;
  } else if(d<36){
    int rel=d-24, v=rel/3, i=rel%3;
    #pragma unroll
    for(int u=0;u<4;u++){ float xv=hr[24+u*3+i]; s1+=xv*w1ei[u*4+v]; s2+=xv*w1er[u*4+v]; }
    o1=s1*0.5f; o2=s2*0.5f;
  } else {
    int rel=d-36, v=rel/5, i=rel%5;
    #pragma unroll
    for(int u=0;u<6;u++){ float xv=hr[36+u*5+i]; s1+=xv*w2i[u*6+v]; s2+=xv*w2r[u*6+v]; }
    const float r=0.4082482904638631f;
    o1=s1*r; o2=s2*r;
  }
  h_in[idx]=o1; out[idx]=o2;
}

// ---------------- fused edge kernel: MFMA wv GEMM + role-split consumption --------
// block = 256 threads = 4 waves x 64 edges.
// Phase A (per 96-row chunk): wv[rows][64] = W_f16 @ H_f16 via mfma_f32_16x16x32_f16
//   (one MFMA covers K=32 entirely). A-frags from global wh (coalesced), B-frags from LDS.
// Phase B: wave g consumes output-mult v == g (mod 4); zt from LDS-staged hs;
//   weight value = ONE stride-1 LDS read wvl[row*64+lane].

template<int L1_,int L2_,int L3_,int MUL1,int MULO,int U0,int U1,int XOFF,int YOFF,int WROW,int CGOFF,int OACC>
__device__ __forceinline__ void do_path_rs(const float* __restrict__ hsr, const float* Y,
  const float* __restrict__ wvl, int wave, int lane, const float* __restrict__ cgl, float* acc)
{
  constexpr int N1=2*L1_+1, N2=2*L2_+1, N3=2*L3_+1;
  constexpr int NJ=(MULO+3)/4;
  float M[N1*N3];
  #pragma unroll
  for(int i=0;i<N1;i++){
    #pragma unroll
    for(int k=0;k<N3;k++){
      float s=0.f;
      #pragma unroll
      for(int j=0;j<N2;j++) s += Y[YOFF+j]*cgl[CGOFF+(i*N2+j)*N3+k];
      M[i*N3+k]=s;
    }
  }
  for(int u=U0; u<U1; u++){
    float zt[N3];
    #pragma unroll
    for(int k=0;k<N3;k++){
      float s=0.f;
      #pragma unroll
      for(int i=0;i<N1;i++) s += hsr[XOFF+u*N1+i]*M[i*N3+k];
      zt[k]=s;
    }
    #pragma unroll
    for(int j=0;j<NJ;j++){
      int v = 4*j + wave;
      if(v < MULO){
        float w = wvl[(WROW + (u-U0)*MULO + v)*64 + lane];
        #pragma unroll
        for(int k=0;k<N3;k++) acc[OACC + j*N3 + k] += zt[k]*w;
      }
    }
  }
}

#define MFMA_CHUNK(GROW, NTILES) \
  __syncthreads(); \
  for(int rt=wave; rt<(NTILES); rt+=4){ \
    f16x8 af = *(const f16x8*)(wh + ((GROW) + rt*16 + (lane&15))*NHID + (lane>>4)*8); \
    f32x4 c0={0.f,0.f,0.f,0.f}, c1=c0, c2=c0, c3=c0; \
    c0=__builtin_amdgcn_mfma_f32_16x16x32_f16(af,bf0,c0,0,0,0); \
    c1=__builtin_amdgcn_mfma_f32_16x16x32_f16(af,bf1,c1,0,0,0); \
    c2=__builtin_amdgcn_mfma_f32_16x16x32_f16(af,bf2,c2,0,0,0); \
    c3=__builtin_amdgcn_mfma_f32_16x16x32_f16(af,bf3,c3,0,0,0); \
    int rbase=(rt*16+4*(lane>>4))*64 + (lane&15); \
    _Pragma("unroll") \
    for(int j=0;j<4;j++){ \
      wvl[rbase + j*64 +  0]=c0[j]; \
      wvl[rbase + j*64 + 16]=c1[j]; \
      wvl[rbase + j*64 + 32]=c2[j]; \
      wvl[rbase + j*64 + 48]=c3[j]; \
    } \
  } \
  __syncthreads();

__global__ __launch_bounds__(256, 3) void edge_fused_kernel(
  const float* __restrict__ h_in, const int* __restrict__ e_src, const int* __restrict__ e_dst,
  const float* __restrict__ e_attr, const float* __restrict__ rad_w1,
  const _Float16* __restrict__ wh, const float* __restrict__ cg, float* __restrict__ out,
  int BE, int N, int E)
{
  __shared__ float hsl[64*HSTR];        // 17.2 KB staged h_in rows
  __shared__ float wvl[96*64];          // 24.6 KB wv chunk
  __shared__ _Float16 Hlds[64*HPAD];    // 5.1 KB hid (f16)
  __shared__ float cgl[640];
  int tid  = threadIdx.x;
  int lane = tid & 63;
  int wave = tid >> 6;
  int e0   = blockIdx.x*64;
  int el   = e0 + lane;
  bool active = el < BE;

  for(int i=tid; i<621; i+=256) cgl[i]=cg[i];

  // stage hs rows (gather once per block)
  for(int i=tid; i<64*DIM; i+=256){
    int e=i/DIM, d=i-e*DIM;
    int ee=e0+e;
    float v=0.f;
    if(ee<BE){
      int bb=ee/E;
      int s=e_src[ee];
      v=h_in[((long)bb*N+s)*DIM+d];
    }
    hsl[e*HSTR+d]=v;
  }

  // per-lane edge data
  int b=0,dst=0;
  float x=0.f,y=0.f,z=0.f;
  if(active){
    b=el/E; dst=e_dst[el];
    const float* ea=e_attr+(long)el*3;
    x=ea[0]; y=ea[1]; z=ea[2];
  }
  float rn=sqrtf(x*x+y*y+z*z)+1e-8f;
  float xh=x/rn, yh=y/rn, zh=z/rn;
  float Y[9];
  const float s3=1.7320508075688772f, s5=2.23606797749979f, s15=3.872983346207417f;
  Y[0]=1.f; Y[1]=s3*yh; Y[2]=s3*zh; Y[3]=s3*xh;
  Y[4]=s15*xh*yh; Y[5]=s15*yh*zh; Y[6]=0.5f*s5*(3.f*zh*zh-1.f);
  Y[7]=s15*xh*zh; Y[8]=0.5f*s15*(xh*xh-yh*yh);

  // stage hid (f16): thread (wave,lane) computes t = wave*8..+7 for its lane-edge
  #pragma unroll
  for(int j=0;j<8;j++){
    int t = wave*8 + j;
    float a = rn*rad_w1[t];
    Hlds[lane*HPAD + t] = (_Float16)(a/(1.f+expf(-a)));
  }
  __syncthreads();

  // B fragments (held all kernel): col=edge et*16+(l&15), k=(l>>4)*8..+7
  f16x8 bf0 = *(const f16x8*)(Hlds + ( 0 + (lane&15))*HPAD + (lane>>4)*8);
  f16x8 bf1 = *(const f16x8*)(Hlds + (16 + (lane&15))*HPAD + (lane>>4)*8);
  f16x8 bf2 = *(const f16x8*)(Hlds + (32 + (lane&15))*HPAD + (lane>>4)*8);
  f16x8 bf3 = *(const f16x8*)(Hlds + (48 + (lane&15))*HPAD + (lane>>4)*8);

  const float* hsr = hsl + lane*HSTR;
  float* op = out + ((long)b*N + dst)*DIM;
  float acc[19];
  #pragma unroll
  for(int i=0;i<19;i++) acc[i]=0.f;

  // ---- chunk schedule: 96-row grid over group-packed rows; u-splits on MULO bounds ----
  MFMA_CHUNK(0, 6)      // C0 rows 0-96
  //          L1 L2 L3 M1 MO  U0 U1  XO YO WROW CGOFF OACC
  do_path_rs<0,0,0,12,12,  0, 8,  0,0,   0,   0, 0>(hsr,Y,wvl,wave,lane,cgl,acc);
  MFMA_CHUNK(96, 6)     // C1 rows 96-192
  do_path_rs<0,0,0,12,12,  8,12,  0,0,   0,   0, 0>(hsr,Y,wvl,wave,lane,cgl,acc);
  do_path_rs<1,1,0, 4,12,  0, 4, 12,1,  48,  44, 0>(hsr,Y,wvl,wave,lane,cgl,acc);
  MFMA_CHUNK(192, 6)    // C2 rows 192-288
  do_path_rs<2,2,0, 6,12,  0, 6, 36,4,   0, 396, 0>(hsr,Y,wvl,wave,lane,cgl,acc);
  do_path_rs<0,1,1,12, 4,  0, 6,  0,1,  72,   1, 3>(hsr,Y,wvl,wave,lane,cgl,acc);
  MFMA_CHUNK(288, 6)    // C3 rows 288-384
  do_path_rs<0,1,1,12, 4,  6,12,  0,1,   0,   1, 3>(hsr,Y,wvl,wave,lane,cgl,acc);
  do_path_rs<1,0,1, 4, 4,  0, 4, 12,0,  24,  35, 3>(hsr,Y,wvl,wave,lane,cgl,acc);
  do_path_rs<1,2,1, 4, 4,  0, 4, 12,4,  40, 125, 3>(hsr,Y,wvl,wave,lane,cgl,acc);
  do_path_rs<1,1,1, 4, 4,  0, 4, 24,1,  56, 179, 3>(hsr,Y,wvl,wave,lane,cgl,acc);
  do_path_rs<2,1,1, 6, 4,  0, 6, 36,1,  72, 351, 3>(hsr,Y,wvl,wave,lane,cgl,acc);
  MFMA_CHUNK(384, 6)    // C4 rows 384-480
  do_path_rs<1,1,1, 4, 4,  0, 4, 12,1,   0,  53, 6>(hsr,Y,wvl,wave,lane,cgl,acc);
  do_path_rs<1,0,1, 4, 4,  0, 4, 24,0,  16, 170, 6>(hsr,Y,wvl,wave,lane,cgl,acc);
  do_path_rs<1,2,1, 4, 4,  0, 4, 24,4,  32, 206, 6>(hsr,Y,wvl,wave,lane,cgl,acc);
  do_path_rs<2,2,1, 6, 4,  0, 6, 36,4,  48, 421, 6>(hsr,Y,wvl,wave,lane,cgl,acc);
  do_path_rs<0,2,2,12, 6,  0, 4,  0,4,  72,  10, 9>(hsr,Y,wvl,wave,lane,cgl,acc);
  MFMA_CHUNK(480, 6)    // C5 rows 480-576
  do_path_rs<0,2,2,12, 6,  4,12,  0,4,   0,  10, 9>(hsr,Y,wvl,wave,lane,cgl,acc);
  do_path_rs<1,1,2, 4, 6,  0, 4, 12,1,  48,  80, 9>(hsr,Y,wvl,wave,lane,cgl,acc);
  do_path_rs<1,2,2, 4, 6,  0, 4, 24,4,  72, 251, 9>(hsr,Y,wvl,wave,lane,cgl,acc);
  MFMA_CHUNK(576, 5)    // C6 rows 576-656 (648-655 zero-padded)
  do_path_rs<2,0,2, 6, 6,  0, 6, 36,0,   0, 326, 9>(hsr,Y,wvl,wave,lane,cgl,acc);
  do_path_rs<2,2,2, 6, 6,  0, 6, 36,4,  36, 496, 9>(hsr,Y,wvl,wave,lane,cgl,acc);

  // ---- atomic scatter: each wave writes its owned channels ----
  if(active){
    const float a0=0.21320071635561044f; // sqrt(1/22)
    const float a1=0.31622776601683794f; // sqrt(3/30)
    const float a2=0.4082482904638631f;  // sqrt(3/18)
    const float a3=0.3952847075210474f;  // sqrt(5/32)
    #pragma unroll
    for(int j=0;j<3;j++) unsafeAtomicAdd(&op[4*j+wave], acc[j]*a0);          // g0
    #pragma unroll
    for(int k=0;k<3;k++) unsafeAtomicAdd(&op[12+wave*3+k], acc[3+k]*a1);     // g1
    #pragma unroll
    for(int k=0;k<3;k++) unsafeAtomicAdd(&op[24+wave*3+k], acc[6+k]*a2);     // g2
    #pragma unroll
    for(int j=0;j<2;j++){                                                     // g3
      int v=4*j+wave;
      if(v<6){
        #pragma unroll
        for(int k=0;k<5;k++) unsafeAtomicAdd(&op[36+v*5+k], acc[9+5*j+k]*a3);
      }
    }
  }
}

// ---------------- norm_act (in place on d_out) ----------------

__global__ void norm_act_kernel(float* __restrict__ out, int total){
  int idx=blockIdx.x*blockDim.x+threadIdx.x;
  if(idx>=total) return;
  int c = idx % 26; long bn = idx / 26;
  int off, len;
  if(c<12){ off=c; len=1; }
  else if(c<16){ off=12+(c-12)*3; len=3; }
  else if(c<20){ off=24+(c-16)*3; len=3; }
  else { off=36+(c-20)*5; len=5; }
  float* p = out + bn*(long)DIM + off;
  float sum=0.f;
  for(int i=0;i<len;i++){ float v=p[i]; sum+=v*v; }
  float n = sqrtf(sum+1e-12f);
  float sc = 1.f/(1.f+expf(-n));  // silu(n)/n = sigmoid(n)
  for(int i=0;i<len;i++) p[i]*=sc;
}

// ---------------- launch ----------------

extern "C" void kernel_launch(void* const* d_in, const int* in_sizes, int n_in,
                              void* d_out, int out_size, void* d_ws, size_t ws_size,
                              hipStream_t stream)
{
  const float* h       = (const float*)d_in[0];
  const int*   e_src   = (const int*)  d_in[1];
  const int*   e_dst   = (const int*)  d_in[2];
  const float* e_attr  = (const float*)d_in[3];
  const float* lw0     = (const float*)d_in[4];
  const float* lw1o    = (const float*)d_in[5];
  const float* lw1e    = (const float*)d_in[6];
  const float* lw2     = (const float*)d_in[7];
  const float* lb0     = (const float*)d_in[8];
  const float* rw0     = (const float*)d_in[9];
  const float* rw1o    = (const float*)d_in[10];
  const float* rw1e    = (const float*)d_in[11];
  const float* rw2     = (const float*)d_in[12];
  const float* rb0     = (const float*)d_in[13];
  const float* rad_w1  = (const float*)d_in[14];
  const float* rad_w2  = (const float*)d_in[15];

  const int B  = 2;
  const int BE = in_sizes[1];        // B*E
  const int E  = BE / B;
  const int BN = in_sizes[0] / DIM;  // B*N
  const int N  = BN / B;

  float* ws   = (float*)d_ws;
  float* h_in = ws;                                   // BN*DIM floats
  float* cg   = ws + (size_t)BN*DIM;                  // 621 floats (pad to 640)
  _Float16* wh = (_Float16*)(cg + 640);               // WROWS*NHID halves (f16, packed)

  cg_init_kernel<<<NPATH, 128, 0, stream>>>(cg);
  int whn = WROWS*NHID;
  wh_pack_kernel<<<(whn+255)/256, 256, 0, stream>>>(rad_w2, wh);
  int totL = BN*DIM;
  linear_kernel<<<(totL+255)/256, 256, 0, stream>>>(h, lw0, lw1o, lw1e, lw2, lb0,
                                                    rw0, rw1o, rw1e, rw2, rb0,
                                                    h_in, (float*)d_out, totL);
  int eblk = (BE+63)/64;
  edge_fused_kernel<<<eblk, 256, 0, stream>>>(h_in, e_src, e_dst, e_attr,
                                              rad_w1, wh, cg, (float*)d_out,
                                              BE, N, E);
  int totN = BN*26;
  norm_act_kernel<<<(totN+255)/256, 256, 0, stream>>>((float*)d_out, totN);
}

// Round 17
// 466.329 us; speedup vs baseline: 4.5954x; 1.0286x over previous
//
#include <hip/hip_runtime.h>
#include <math.h>

#define DIM 66
#define NPATH 17
#define WNUM 648
#define NHID 32
#define HPAD 40   // Hlds halves per edge (80B stride, 16B-aligned b128)
#define WROWS 656 // 648 rounded to 16

typedef _Float16 f16x8 __attribute__((ext_vector_type(8)));
typedef float f32x4 __attribute__((ext_vector_type(4)));

// ---------------- CG computation (device, mirrors reference exactly) ----------------

__device__ double dfact(int n){ double f=1.0; for(int i=2;i<=n;i++) f*=(double)i; return f; }

__device__ double su2_cg(int j1,int j2,int j3,int m1,int m2,int m3){
  if(m1+m2!=m3) return 0.0;
  double pre = sqrt((double)(2*j3+1)*dfact(j3+j1-j2)*dfact(j3-j1+j2)*dfact(j1+j2-j3)/dfact(j1+j2+j3+1));
  pre *= sqrt(dfact(j3+m3)*dfact(j3-m3)*dfact(j1-m1)*dfact(j1+m1)*dfact(j2-m2)*dfact(j2+m2));
  double s=0.0;
  for(int k=0;k<=j1+j2-j3;k++){
    int a0=k, a1=j1+j2-j3-k, a2=j1-m1-k, a3=j2+m2-k, a4=j3-j2+m1+k, a5=j3-j1-m2+k;
    if(a0<0||a1<0||a2<0||a3<0||a4<0||a5<0) continue;
    double d = dfact(a0)*dfact(a1)*dfact(a2)*dfact(a3)*dfact(a4)*dfact(a5);
    s += ((k&1)? -1.0:1.0)/d;
  }
  return pre*s;
}

__device__ void u_real_entry(int l, int row, int col, double& re, double& im){
  re=0.0; im=0.0;
  const double sq = 0.7071067811865476;
  int m = row - l;
  if(m>0){
    if(col==l+m) re = ((m&1)? -sq : sq);
    else if(col==l-m) re = sq;
  } else if(m==0){
    if(col==l) re = 1.0;
  } else {
    int am = -m;
    if(col==l+m) im = sq;
    else if(col==l-m) im = ((am&1)? sq : -sq);
  }
}

__constant__ int c_l1[NPATH]   = {0,0,0,1,1,1,1,1,1,1,1,1,2,2,2,2,2};
__constant__ int c_l2[NPATH]   = {0,1,2,0,1,1,1,2,0,1,2,2,0,1,2,2,2};
__constant__ int c_l3[NPATH]   = {0,1,2,1,0,1,2,1,1,1,1,2,2,1,0,1,2};
__constant__ int c_cgoff[NPATH]= {0,1,10,35,44,53,80,125,170,179,206,251,326,351,396,421,496};

__global__ void cg_init_kernel(float* __restrict__ cg_out){
  int p = blockIdx.x;
  int l1=c_l1[p], l2=c_l2[p], l3=c_l3[p];
  int n1=2*l1+1, n2=2*l2+1, n3=2*l3+1;
  int ntot=n1*n2*n3;
  __shared__ double Cc[125];
  __shared__ double red[128];
  int t=threadIdx.x;
  if(t<ntot){
    int i=t/(n2*n3), j=(t/n3)%n2, k=t%n3;
    Cc[t] = su2_cg(l1,l2,l3,i-l1,j-l2,k-l3);
  }
  __syncthreads();
  double Tre=0.0, Tim=0.0;
  if(t<ntot){
    int a=t/(n2*n3), b=(t/n3)%n2, c=t%n3;
    for(int i=0;i<n1;i++)for(int j=0;j<n2;j++)for(int k=0;k<n3;k++){
      double cc=Cc[(i*n2+j)*n3+k];
      if(cc==0.0) continue;
      double u1r,u1i,u2r,u2i,u3r,u3i;
      u_real_entry(l1,a,i,u1r,u1i); u1i=-u1i;
      u_real_entry(l2,b,j,u2r,u2i); u2i=-u2i;
      u_real_entry(l3,c,k,u3r,u3i);
      double pr=u1r*u2r-u1i*u2i, pi=u1r*u2i+u1i*u2r;
      double qr=pr*u3r-pi*u3i,   qi=pr*u3i+pi*u3r;
      Tre+=qr*cc; Tim+=qi*cc;
    }
  }
  red[t]=fabs(Tre); __syncthreads();
  for(int s=64;s>0;s>>=1){ if(t<s) red[t]+=red[t+s]; __syncthreads(); }
  double sar=red[0]; __syncthreads();
  red[t]=fabs(Tim); __syncthreads();
  for(int s=64;s>0;s>>=1){ if(t<s) red[t]+=red[t+s]; __syncthreads(); }
  double sai=red[0]; __syncthreads();
  double chosen = (sar>=sai)? Tre : Tim;
  red[t]=chosen*chosen; __syncthreads();
  for(int s=64;s>0;s>>=1){ if(t<s) red[t]+=red[t+s]; __syncthreads(); }
  double nrm=sqrt(red[0]);
  if(t<ntot) cg_out[c_cgoff[p]+t] = (float)(chosen/nrm);
}

// ------- W repack to f16: transpose + 1/sqrt(32) + group-contiguous rows, zero-pad to 656 -------

__constant__ int rp_old[NPATH] = {0,144,192,264,280,328,344,368,384,400,416,432,456,492,516,588,612};
__constant__ int rp_cnt[NPATH] = {144,48,72,16,48,16,24,16,16,16,16,24,36,24,72,24,36};
__constant__ int rp_new[NPATH] = {0,264,456,312,144,384,528,328,400,344,416,552,576,360,192,432,612};

__global__ void wh_pack_kernel(const float* __restrict__ w2, _Float16* __restrict__ wh){
  int i=blockIdx.x*blockDim.x+threadIdx.x;
  if(i>=WROWS*NHID) return;
  int nr=i>>5, t=i&31;
  float val=0.f;
  #pragma unroll
  for(int p=0;p<NPATH;p++){
    if(nr>=rp_new[p] && nr<rp_new[p]+rp_cnt[p]){
      int c = rp_old[p] + (nr - rp_new[p]);
      val = w2[t*WNUM + c]*0.17677669529663687f; // 1/sqrt(32)
    }
  }
  wh[i]=(_Float16)val;
}

// ---------------- per-node linears: h_in (lin_in) to ws, res to d_out ----------------

__global__ void linear_kernel(const float* __restrict__ h,
  const float* __restrict__ w0i, const float* __restrict__ w1oi, const float* __restrict__ w1ei,
  const float* __restrict__ w2i, const float* __restrict__ b0i,
  const float* __restrict__ w0r, const float* __restrict__ w1or_, const float* __restrict__ w1er,
  const float* __restrict__ w2r, const float* __restrict__ b0r,
  float* __restrict__ h_in, float* __restrict__ out, int total)
{
  int idx=blockIdx.x*blockDim.x+threadIdx.x;
  if(idx>=total) return;
  int d = idx % DIM;
  long bn = idx / DIM;
  const float* hr = h + bn*(long)DIM;
  float s1=0.f, s2=0.f, o1, o2;
  if(d<12){
    #pragma unroll
    for(int u=0;u<12;u++){ float xv=hr[u]; s1+=xv*w0i[u*12+d]; s2+=xv*w0r[u*12+d]; }
    const float r = 0.28867513459481287f;
    o1 = s1*r + b0i[d]; o2 = s2*r + b0r[d];
  } else if(d<24){
    int rel=d-12, v=rel/3, i=rel%3;
    #pragma unroll
    for(int u=0;u<4;u++){ float xv=hr[12+u*3+i]; s1+=xv*w1oi[u*4+v]; s2+=xv*w1or_[u*4+v]; }
    o1=s1*0.5f; o2=s2*0.5f;
  } else if(d<36){
    int rel=d-24, v=rel/3, i=rel%3;
    #pragma unroll
    for(int u=0;u<4;u++){ float xv=hr[24+u*3+i]; s1+=xv*w1ei[u*4+v]; s2+=xv*w1er[u*4+v]; }
    o1=s1*0.5f; o2=s2*0.5f;
  } else {
    int rel=d-36, v=rel/5, i=rel%5;
    #pragma unroll
    for(int u=0;u<6;u++){ float xv=hr[36+u*5+i]; s1+=xv*w2i[u*6+v]; s2+=xv*w2r[u*6+v]; }
    const float r=0.4082482904638631f;
    o1=s1*r; o2=s2*r;
  }
  h_in[idx]=o1; out[idx]=o2;
}

// ---------------- fused edge kernel: MFMA wv GEMM + role-split consumption --------
// block = 256 threads = 4 waves x 64 edges.
// Phase A (per 96-row chunk): wv = W_f16 @ H_f16 via mfma_f32_16x16x32_f16; output
//   written to LDS with 2-row column rotation (wvx) -> 2-way banks (free).
// Phase B: hs in REGISTERS (u-loops fully unrolled -> static indexing); wave g
//   consumes v == g (mod 4); weight value = one stride-1 LDS read.

__device__ __forceinline__ int wvx(int r, int c){ return r*64 + ((c + 2*r) & 63); }

template<int L1_,int L2_,int L3_,int MUL1,int MULO,int U0,int U1,int XOFF,int YOFF,int WROW,int CGOFF,int OACC>
__device__ __forceinline__ void do_path_rs(const float* __restrict__ hsv, const float* Y,
  const float* __restrict__ wvl, int wave, int lane, const float* __restrict__ cgl, float* acc)
{
  constexpr int N1=2*L1_+1, N2=2*L2_+1, N3=2*L3_+1;
  constexpr int NJ=(MULO+3)/4;
  float M[N1*N3];
  #pragma unroll
  for(int i=0;i<N1;i++){
    #pragma unroll
    for(int k=0;k<N3;k++){
      float s=0.f;
      #pragma unroll
      for(int j=0;j<N2;j++) s += Y[YOFF+j]*cgl[CGOFF+(i*N2+j)*N3+k];
      M[i*N3+k]=s;
    }
  }
  #pragma unroll
  for(int u=U0; u<U1; u++){
    float zt[N3];
    #pragma unroll
    for(int k=0;k<N3;k++){
      float s=0.f;
      #pragma unroll
      for(int i=0;i<N1;i++) s += hsv[XOFF+u*N1+i]*M[i*N3+k];
      zt[k]=s;
    }
    #pragma unroll
    for(int j=0;j<NJ;j++){
      int v = 4*j + wave;
      if(v < MULO){
        float w = wvl[wvx(WROW + (u-U0)*MULO + v, lane)];
        #pragma unroll
        for(int k=0;k<N3;k++) acc[OACC + j*N3 + k] += zt[k]*w;
      }
    }
  }
}

#define MFMA_CHUNK(GROW, NTILES) \
  __syncthreads(); \
  for(int rt=wave; rt<(NTILES); rt+=4){ \
    f16x8 af = *(const f16x8*)(wh + ((GROW) + rt*16 + (lane&15))*NHID + (lane>>4)*8); \
    f32x4 c0={0.f,0.f,0.f,0.f}, c1=c0, c2=c0, c3=c0; \
    c0=__builtin_amdgcn_mfma_f32_16x16x32_f16(af,bf0,c0,0,0,0); \
    c1=__builtin_amdgcn_mfma_f32_16x16x32_f16(af,bf1,c1,0,0,0); \
    c2=__builtin_amdgcn_mfma_f32_16x16x32_f16(af,bf2,c2,0,0,0); \
    c3=__builtin_amdgcn_mfma_f32_16x16x32_f16(af,bf3,c3,0,0,0); \
    int rr = rt*16 + 4*(lane>>4); \
    _Pragma("unroll") \
    for(int j=0;j<4;j++){ \
      wvl[wvx(rr+j, (lane&15)+ 0)]=c0[j]; \
      wvl[wvx(rr+j, (lane&15)+16)]=c1[j]; \
      wvl[wvx(rr+j, (lane&15)+32)]=c2[j]; \
      wvl[wvx(rr+j, (lane&15)+48)]=c3[j]; \
    } \
  } \
  __syncthreads();

__global__ __launch_bounds__(256, 2) void edge_fused_kernel(
  const float* __restrict__ h_in, const int* __restrict__ e_src, const int* __restrict__ e_dst,
  const float* __restrict__ e_attr, const float* __restrict__ rad_w1,
  const _Float16* __restrict__ wh, const float* __restrict__ cg, float* __restrict__ out,
  int BE, int N, int E)
{
  __shared__ float wvl[96*64];          // 24.6 KB wv chunk (rotated layout)
  __shared__ _Float16 Hlds[64*HPAD];    // 5.1 KB hid (f16)
  __shared__ float cgl[640];
  int tid  = threadIdx.x;
  int lane = tid & 63;
  int wave = tid >> 6;
  int e0   = blockIdx.x*64;
  int el   = e0 + lane;
  bool active = el < BE;

  for(int i=tid; i<621; i+=256) cgl[i]=cg[i];

  // per-lane edge data
  int b=0,dst=0;
  float x=0.f,y=0.f,z=0.f;
  if(active){
    b=el/E; dst=e_dst[el];
    const float* ea=e_attr+(long)el*3;
    x=ea[0]; y=ea[1]; z=ea[2];
  }
  float rn=sqrtf(x*x+y*y+z*z)+1e-8f;
  float xh=x/rn, yh=y/rn, zh=z/rn;
  float Y[9];
  const float s3=1.7320508075688772f, s5=2.23606797749979f, s15=3.872983346207417f;
  Y[0]=1.f; Y[1]=s3*yh; Y[2]=s3*zh; Y[3]=s3*xh;
  Y[4]=s15*xh*yh; Y[5]=s15*yh*zh; Y[6]=0.5f*s5*(3.f*zh*zh-1.f);
  Y[7]=s15*xh*zh; Y[8]=0.5f*s15*(xh*xh-yh*yh);

  // hs row -> registers (66 independent global loads, L1-shared across waves)
  int src = active ? e_src[el] : 0;
  const float* hp = h_in + ((long)b*N + src)*DIM;
  float hsv[DIM];
  #pragma unroll
  for(int d=0;d<DIM;d++) hsv[d]=hp[d];

  // stage hid (f16): thread (wave,lane) computes t = wave*8..+7 for its lane-edge
  #pragma unroll
  for(int j=0;j<8;j++){
    int t = wave*8 + j;
    float a = rn*rad_w1[t];
    Hlds[lane*HPAD + t] = (_Float16)(a/(1.f+expf(-a)));
  }
  __syncthreads();

  // B fragments (held all kernel): col=edge et*16+(l&15), k=(l>>4)*8..+7
  f16x8 bf0 = *(const f16x8*)(Hlds + ( 0 + (lane&15))*HPAD + (lane>>4)*8);
  f16x8 bf1 = *(const f16x8*)(Hlds + (16 + (lane&15))*HPAD + (lane>>4)*8);
  f16x8 bf2 = *(const f16x8*)(Hlds + (32 + (lane&15))*HPAD + (lane>>4)*8);
  f16x8 bf3 = *(const f16x8*)(Hlds + (48 + (lane&15))*HPAD + (lane>>4)*8);

  float* op = out + ((long)b*N + dst)*DIM;
  float acc[19];
  #pragma unroll
  for(int i=0;i<19;i++) acc[i]=0.f;

  // ---- chunk schedule (same tables as R16 pass): 96-row grid, group-packed rows ----
  MFMA_CHUNK(0, 6)      // C0 rows 0-96
  //          L1 L2 L3 M1 MO  U0 U1  XO YO WROW CGOFF OACC
  do_path_rs<0,0,0,12,12,  0, 8,  0,0,   0,   0, 0>(hsv,Y,wvl,wave,lane,cgl,acc);
  MFMA_CHUNK(96, 6)     // C1 rows 96-192
  do_path_rs<0,0,0,12,12,  8,12,  0,0,   0,   0, 0>(hsv,Y,wvl,wave,lane,cgl,acc);
  do_path_rs<1,1,0, 4,12,  0, 4, 12,1,  48,  44, 0>(hsv,Y,wvl,wave,lane,cgl,acc);
  MFMA_CHUNK(192, 6)    // C2 rows 192-288
  do_path_rs<2,2,0, 6,12,  0, 6, 36,4,   0, 396, 0>(hsv,Y,wvl,wave,lane,cgl,acc);
  do_path_rs<0,1,1,12, 4,  0, 6,  0,1,  72,   1, 3>(hsv,Y,wvl,wave,lane,cgl,acc);
  MFMA_CHUNK(288, 6)    // C3 rows 288-384
  do_path_rs<0,1,1,12, 4,  6,12,  0,1,   0,   1, 3>(hsv,Y,wvl,wave,lane,cgl,acc);
  do_path_rs<1,0,1, 4, 4,  0, 4, 12,0,  24,  35, 3>(hsv,Y,wvl,wave,lane,cgl,acc);
  do_path_rs<1,2,1, 4, 4,  0, 4, 12,4,  40, 125, 3>(hsv,Y,wvl,wave,lane,cgl,acc);
  do_path_rs<1,1,1, 4, 4,  0, 4, 24,1,  56, 179, 3>(hsv,Y,wvl,wave,lane,cgl,acc);
  do_path_rs<2,1,1, 6, 4,  0, 6, 36,1,  72, 351, 3>(hsv,Y,wvl,wave,lane,cgl,acc);
  MFMA_CHUNK(384, 6)    // C4 rows 384-480
  do_path_rs<1,1,1, 4, 4,  0, 4, 12,1,   0,  53, 6>(hsv,Y,wvl,wave,lane,cgl,acc);
  do_path_rs<1,0,1, 4, 4,  0, 4, 24,0,  16, 170, 6>(hsv,Y,wvl,wave,lane,cgl,acc);
  do_path_rs<1,2,1, 4, 4,  0, 4, 24,4,  32, 206, 6>(hsv,Y,wvl,wave,lane,cgl,acc);
  do_path_rs<2,2,1, 6, 4,  0, 6, 36,4,  48, 421, 6>(hsv,Y,wvl,wave,lane,cgl,acc);
  do_path_rs<0,2,2,12, 6,  0, 4,  0,4,  72,  10, 9>(hsv,Y,wvl,wave,lane,cgl,acc);
  MFMA_CHUNK(480, 6)    // C5 rows 480-576
  do_path_rs<0,2,2,12, 6,  4,12,  0,4,   0,  10, 9>(hsv,Y,wvl,wave,lane,cgl,acc);
  do_path_rs<1,1,2, 4, 6,  0, 4, 12,1,  48,  80, 9>(hsv,Y,wvl,wave,lane,cgl,acc);
  do_path_rs<1,2,2, 4, 6,  0, 4, 24,4,  72, 251, 9>(hsv,Y,wvl,wave,lane,cgl,acc);
  MFMA_CHUNK(576, 5)    // C6 rows 576-656 (648-655 zero-padded)
  do_path_rs<2,0,2, 6, 6,  0, 6, 36,0,   0, 326, 9>(hsv,Y,wvl,wave,lane,cgl,acc);
  do_path_rs<2,2,2, 6, 6,  0, 6, 36,4,  36, 496, 9>(hsv,Y,wvl,wave,lane,cgl,acc);

  // ---- atomic scatter: each wave writes its owned channels ----
  if(active){
    const float a0=0.21320071635561044f; // sqrt(1/22)
    const float a1=0.31622776601683794f; // sqrt(3/30)
    const float a2=0.4082482904638631f;  // sqrt(3/18)
    const float a3=0.3952847075210474f;  // sqrt(5/32)
    #pragma unroll
    for(int j=0;j<3;j++) unsafeAtomicAdd(&op[4*j+wave], acc[j]*a0);          // g0
    #pragma unroll
    for(int k=0;k<3;k++) unsafeAtomicAdd(&op[12+wave*3+k], acc[3+k]*a1);     // g1
    #pragma unroll
    for(int k=0;k<3;k++) unsafeAtomicAdd(&op[24+wave*3+k], acc[6+k]*a2);     // g2
    #pragma unroll
    for(int j=0;j<2;j++){                                                     // g3
      int v=4*j+wave;
      if(v<6){
        #pragma unroll
        for(int k=0;k<5;k++) unsafeAtomicAdd(&op[36+v*5+k], acc[9+5*j+k]*a3);
      }
    }
  }
}

// ---------------- norm_act (in place on d_out) ----------------

__global__ void norm_act_kernel(float* __restrict__ out, int total){
  int idx=blockIdx.x*blockDim.x+threadIdx.x;
  if(idx>=total) return;
  int c = idx % 26; long bn = idx / 26;
  int off, len;
  if(c<12){ off=c; len=1; }
  else if(c<16){ off=12+(c-12)*3; len=3; }
  else if(c<20){ off=24+(c-16)*3; len=3; }
  else { off=36+(c-20)*5; len=5; }
  float* p = out + bn*(long)DIM + off;
  float sum=0.f;
  for(int i=0;i<len;i++){ float v=p[i]; sum+=v*v; }
  float n = sqrtf(sum+1e-12f);
  float sc = 1.f/(1.f+expf(-n));  // silu(n)/n = sigmoid(n)
  for(int i=0;i<len;i++) p[i]*=sc;
}

// ---------------- launch ----------------

extern "C" void kernel_launch(void* const* d_in, const int* in_sizes, int n_in,
                              void* d_out, int out_size, void* d_ws, size_t ws_size,
                              hipStream_t stream)
{
  const float* h       = (const float*)d_in[0];
  const int*   e_src   = (const int*)  d_in[1];
  const int*   e_dst   = (const int*)  d_in[2];
  const float* e_attr  = (const float*)d_in[3];
  const float* lw0     = (const float*)d_in[4];
  const float* lw1o    = (const float*)d_in[5];
  const float* lw1e    = (const float*)d_in[6];
  const float* lw2     = (const float*)d_in[7];
  const float* lb0     = (const float*)d_in[8];
  const float* rw0     = (const float*)d_in[9];
  const float* rw1o    = (const float*)d_in[10];
  const float* rw1e    = (const float*)d_in[11];
  const float* rw2     = (const float*)d_in[12];
  const float* rb0     = (const float*)d_in[13];
  const float* rad_w1  = (const float*)d_in[14];
  const float* rad_w2  = (const float*)d_in[15];

  const int B  = 2;
  const int BE = in_sizes[1];        // B*E
  const int E  = BE / B;
  const int BN = in_sizes[0] / DIM;  // B*N
  const int N  = BN / B;

  float* ws   = (float*)d_ws;
  float* h_in = ws;                                   // BN*DIM floats
  float* cg   = ws + (size_t)BN*DIM;                  // 621 floats (pad to 640)
  _Float16* wh = (_Float16*)(cg + 640);               // WROWS*NHID halves (f16, packed)

  cg_init_kernel<<<NPATH, 128, 0, stream>>>(cg);
  int whn = WROWS*NHID;
  wh_pack_kernel<<<(whn+255)/256, 256, 0, stream>>>(rad_w2, wh);
  int totL = BN*DIM;
  linear_kernel<<<(totL+255)/256, 256, 0, stream>>>(h, lw0, lw1o, lw1e, lw2, lb0,
                                                    rw0, rw1o, rw1e, rw2, rb0,
                                                    h_in, (float*)d_out, totL);
  int eblk = (BE+63)/64;
  edge_fused_kernel<<<eblk, 256, 0, stream>>>(h_in, e_src, e_dst, e_attr,
                                              rad_w1, wh, cg, (float*)d_out,
                                              BE, N, E);
  int totN = BN*26;
  norm_act_kernel<<<(totN+255)/256, 256, 0, stream>>>((float*)d_out, totN);
}